// Round 10
// baseline (3576.138 us; speedup 1.0000x reference)
//
#include <hip/hip_runtime.h>
#include <math.h>

// ---------------------------------------------------------------------------
// TDS decoder R14: R13 (993us: replicated poll counters) + SINGLE-GATHERER
// decide with replicated 8B result broadcast.
//  - All blocks: replicated counter poll (go signal for gh loads) as R13.
//  - Block 0 only: hp read + 64-region gather (sole reader -> no camping) +
//    argmax + o[] writes, then broadcasts {(t<<6)|best, S} to 16 replica
//    lines in ONE store instruction (lanes 0-15).
//  - Blocks 1..255: wave0 lane0 polls replica (b&15) -> 16 readers/line,
//    sets sc_lds/bf_lds. GRU waves unchanged (spin bf_lds, gh gated by go).
//  - Overwrite-safe without rotation: result(t+1) requires all blocks to
//    have released t+1, which requires each to have observed result(t).
//  - Push path unchanged from R11/R13: early reduce+atomicAdd before
//    barrier C, 8 relaxed replica-counter RMWs after.
// ---------------------------------------------------------------------------

#define NV      40
#define TENC    8192
#define MAXLEN  200
#define EOS_IDX 38
#define NB      256
#define NT      1024
#define NW      16
#define ROWS    32
#define NG      64                    /* groups of NB/NG=4 blocks           */
#define GSTRIDE 192                   /* floats per group region            */
#define CREP    64                    /* first replica counter col          */
#define NRES    16                    /* result replicas (64B apart)        */
#define HPOFF   (NG * GSTRIDE)        /* 12288: hp line within slot         */
#define SLOT    (HPOFF + 64)          /* 12352 floats per rotation slot     */
#define SCALE   0.04419417382415922f  /* 1/sqrt(512) */

#define WS_RES  0                     /* 16 replicas x 16 floats = 256      */
#define WS_ACC  256                   /* float[3][SLOT]                     */
#define WS_GH   (WS_ACC + 3 * SLOT)   /* 37312: float[3][1536]              */
#define WS_GI   (WS_GH + 3 * 1536)    /* 41920: float[40*1536]              */

typedef unsigned long long u64;

__device__ __forceinline__ int ld_ai(int* p) {
  return __hip_atomic_load(p, __ATOMIC_RELAXED, __HIP_MEMORY_SCOPE_AGENT);
}
__device__ __forceinline__ float ld_af(float* p) {
  return __hip_atomic_load(p, __ATOMIC_RELAXED, __HIP_MEMORY_SCOPE_AGENT);
}
__device__ __forceinline__ void st_af(float* p, float v) {
  __hip_atomic_store(p, v, __ATOMIC_RELAXED, __HIP_MEMORY_SCOPE_AGENT);
}
__device__ __forceinline__ void st_ai(int* p, int v) {
  __hip_atomic_store(p, v, __ATOMIC_RELAXED, __HIP_MEMORY_SCOPE_AGENT);
}
__device__ __forceinline__ u64 ld_u64(float* p) {
  return __hip_atomic_load((u64*)p, __ATOMIC_RELAXED, __HIP_MEMORY_SCOPE_AGENT);
}
__device__ __forceinline__ void st_u64(float* p, u64 v) {
  __hip_atomic_store((u64*)p, v, __ATOMIC_RELAXED, __HIP_MEMORY_SCOPE_AGENT);
}
__device__ __forceinline__ void add_relaxed(int* p) {
  __hip_atomic_fetch_add(p, 1, __ATOMIC_RELAXED, __HIP_MEMORY_SCOPE_AGENT);
}
__device__ __forceinline__ int ld_lds_acq(int* p) {
  return __hip_atomic_load(p, __ATOMIC_ACQUIRE, __HIP_MEMORY_SCOPE_WORKGROUP);
}
__device__ __forceinline__ void st_lds_rel(int* p, int v) {
  __hip_atomic_store(p, v, __ATOMIC_RELEASE, __HIP_MEMORY_SCOPE_WORKGROUP);
}
__device__ __forceinline__ void inc_lds_rel(int* p) {
  __hip_atomic_fetch_add(p, 1, __ATOMIC_RELEASE, __HIP_MEMORY_SCOPE_WORKGROUP);
}

__device__ __forceinline__ float wred(float s) {
#pragma unroll
  for (int o = 32; o > 0; o >>= 1) s += __shfl_xor(s, o, 64);
  return s;
}
__device__ __forceinline__ float dot8(float4 a0, float4 a1, float4 b0,
                                      float4 b1) {
  return a0.x * b0.x + a0.y * b0.y + a0.z * b0.z + a0.w * b0.w +
         a1.x * b1.x + a1.y * b1.y + a1.z * b1.z + a1.w * b1.w;
}
__device__ __forceinline__ float wdot512(const float* __restrict__ a,
                                         const float* __restrict__ b) {
  const int l = threadIdx.x & 63;
  const float4 a0 = ((const float4*)a)[l];
  const float4 a1 = ((const float4*)a)[l + 64];
  const float4 b0 = ((const float4*)b)[l];
  const float4 b1 = ((const float4*)b)[l + 64];
  return wred(dot8(a0, a1, b0, b1));
}

__global__ void dec_init(int* wsi) {
  for (int k = threadIdx.x; k < WS_GH; k += NT) wsi[k] = 0;
}

__global__ void __launch_bounds__(NT, 4) dec_main(
    const float* __restrict__ enc, const float* __restrict__ hidden,
    const float* __restrict__ embed, const float* __restrict__ w_ih,
    const float* __restrict__ w_hh, const float* __restrict__ b_ih,
    const float* __restrict__ b_hh, const float* __restrict__ w_out,
    const float* __restrict__ b_out, float* __restrict__ o,
    float* __restrict__ ws) {
  const int b = blockIdx.x, tid = threadIdx.x;
  const int wave = tid >> 6, lane = tid & 63;
  const int g = b & (NG - 1);
  const int rep = b & 7;
  const int rres = b & (NRES - 1);
  const int r0 = b * ROWS;

  __shared__ __align__(16) float h_lds[512];
  __shared__ float pw_lds[NW * 48];
  __shared__ float sc_lds[1];
  __shared__ int go_lds;  // t+1 when step-t inputs are at the MALL
  __shared__ int bf_lds;  // (t<<6)|best
  __shared__ int pwc;     // monotonic: waves 1-15 inc once per dots phase

  // ----------------- prologue -----------------
  if (tid < 512) h_lds[tid] = hidden[tid];
  if (tid == 0) { go_lds = 0; bf_lds = -1; pwc = 0; }

  // gi_all[v][j] = W_ih[j].embed[v] + b_ih[j]  (240 dots per block)
  for (int u = wave; u < 240; u += NW) {
    const int gl = b * 240 + u;
    const int v = gl / 1536, j = gl - v * 1536;
    const float d = wdot512(w_ih + (size_t)j * 512, embed + (size_t)v * 512);
    if (lane == 0) ws[WS_GI + (size_t)v * 1536 + j] = d + b_ih[j];
  }
  // gh(h0) -> slot 2  (waves 0-5, one row each)
  for (int jr = wave; jr < 6; jr += NW) {
    const int j = b * 6 + jr;
    const float d = wdot512(w_hh + (size_t)j * 512, hidden);
    if (lane == 0) st_af(&ws[WS_GH + 2 * 1536 + j], d + b_hh[j]);
  }
  __syncthreads();  // drain stores
  if (tid == 0) {
    int* cbase = (int*)(ws + WS_ACC + 2 * SLOT + g * GSTRIDE + CREP);
#pragma unroll
    for (int r = 0; r < 8; ++r) add_relaxed(cbase + 16 * r);
  }

  // --- register-resident operands ---
  const float* k0p = enc + (size_t)(r0 + 2 * wave) * 1024;
  const float4 k0a = ((const float4*)k0p)[lane];
  const float4 k0b = ((const float4*)k0p)[lane + 64];
  const float4 k1a = ((const float4*)(k0p + 1024))[lane];
  const float4 k1b = ((const float4*)(k0p + 1024))[lane + 64];

  // M columns: Mr0/Mr1 = W_out[lane,:512].V[row0/1]; lane40 = 1 (S column)
  float Mr0 = (lane == 40) ? 1.0f : 0.0f, Mr1 = Mr0;
  {
    const float* v0p = k0p + 512;
    const float4 va0 = ((const float4*)v0p)[lane];
    const float4 va1 = ((const float4*)v0p)[lane + 64];
    const float4 vb0 = ((const float4*)(v0p + 1024))[lane];
    const float4 vb1 = ((const float4*)(v0p + 1024))[lane + 64];
    for (int v = 0; v < NV; ++v) {
      const float* wp = w_out + (size_t)v * 1024;
      const float4 w0 = ((const float4*)wp)[lane];
      const float4 w1 = ((const float4*)wp)[lane + 64];
      const float sa = wred(dot8(va0, va1, w0, w1));
      const float sb = wred(dot8(vb0, vb1, w0, w1));
      if (lane == v) { Mr0 = sa; Mr1 = sb; }
    }
  }
  // aux row: waves 1-6 -> W_hh row b*6+wave-1; wave 7 (b in 1..40) -> W_out hp
  float4 xa0 = {0, 0, 0, 0}, xa1 = {0, 0, 0, 0};
  float xb = 0.0f;
  if (wave >= 1 && wave <= 6) {
    const int j = b * 6 + (wave - 1);
    const float* wp = w_hh + (size_t)j * 512;
    xa0 = ((const float4*)wp)[lane];
    xa1 = ((const float4*)wp)[lane + 64];
    xb = b_hh[j];
  } else if (wave == 7 && b >= 1 && b <= NV) {
    const float* wp = w_out + (size_t)(b - 1) * 1024 + 512;
    xa0 = ((const float4*)wp)[lane];
    xa1 = ((const float4*)wp)[lane + 64];
    xb = b_out[b - 1];
  }

  // ----------------- main loop -----------------
  int eos_reg = -1;              // block0/wave0/lane0 only
  float p0 = 0.0f, p1 = 0.0f;    // this wave's attention weights (unnorm.)
  float* attn = o + (size_t)MAXLEN * NV + 1;

  for (int t = 0; t <= MAXLEN; ++t) {
    if (wave == 0) {
      float* accs = ws + WS_ACC + ((t + 2) % 3) * SLOT;
      {  // poll all NG counters (sticky; replica b&7 -> 32 readers/line)
        int* cp = (int*)(accs + lane * GSTRIDE + CREP + 16 * rep);
        bool ok = false;
        for (;;) {
          if (!ok) ok = (ld_ai(cp) >= NB / NG);
          if (__ballot(!ok) == 0ull) break;
          __builtin_amdgcn_s_sleep(1);
        }
      }
      if (lane == 0) st_lds_rel(&go_lds, t + 1);  // GRU waves may start gh
      if (t > 0) {
        if (b == 0) {
          // ---- sole gatherer: no read camping on the data lines ----
          const float hp = (lane < NV) ? ld_af(&accs[HPOFF + lane]) : 0.0f;
          float c0 = 0, c1 = 0, c2 = 0, c3 = 0;
#pragma unroll
          for (int q = 0; q < NG / 4; ++q) {
            c0 += ld_af(&accs[(4 * q + 0) * GSTRIDE + lane]);
            c1 += ld_af(&accs[(4 * q + 1) * GSTRIDE + lane]);
            c2 += ld_af(&accs[(4 * q + 2) * GSTRIDE + lane]);
            c3 += ld_af(&accs[(4 * q + 3) * GSTRIDE + lane]);
          }
          const float cs = (c0 + c1) + (c2 + c3);
          const float S = __shfl(cs, NV, 64);
          const float ov = cs * (1.0f / S) + hp;
          unsigned long long key = 0ull;
          if (lane < NV) {
            unsigned u = __float_as_uint(ov);
            u = (u & 0x80000000u) ? ~u : (u | 0x80000000u);
            key = ((unsigned long long)u << 32) | (unsigned)(~lane);
          }
#pragma unroll
          for (int m = 32; m > 0; m >>= 1) {
            const unsigned long long k2 = __shfl_xor(key, m, 64);
            if (k2 > key) key = k2;
          }
          const int best = (int)(~(unsigned)key);
          // broadcast {hi=(t<<6)|best, lo=S} to 16 replica lines (1 instr)
          const u64 res = ((u64)(unsigned)((t << 6) | best) << 32) |
                          (u64)__float_as_uint(S);
          if (lane < NRES) st_u64(ws + WS_RES + 16 * lane, res);
          if (lane < NV) o[(size_t)(t - 1) * NV + lane] = ov;
          if (lane == 0) {
            sc_lds[0] = S;
            if (best == EOS_IDX && eos_reg < 0) eos_reg = t - 1;
            if (t == MAXLEN)
              o[(size_t)MAXLEN * NV] =
                  (eos_reg < 0) ? (float)MAXLEN : (float)eos_reg;
            st_lds_rel(&bf_lds, (t << 6) | best);
          }
        } else if (lane == 0) {
          // ---- result poll: replica b&15 -> 16 readers/line ----
          u64 res;
          for (;;) {
            res = ld_u64(ws + WS_RES + 16 * rres);
            if ((int)(res >> 38) == t) break;
            __builtin_amdgcn_s_sleep(1);
          }
          sc_lds[0] = __uint_as_float((unsigned)res);
          st_lds_rel(&bf_lds, (int)(unsigned)(res >> 32));
        }
      } else if (lane == 0) {
        st_lds_rel(&bf_lds, EOS_IDX);  // (0<<6)|EOS
      }
    } else if (wave >= 8 && t < MAXLEN) {
      // ---- GRU waves: gh loads overlap wave0's decide ----
      const int j = tid - 512;
      while (ld_lds_acq(&go_lds) < t + 1) __builtin_amdgcn_s_sleep(1);
      float* ghs = ws + WS_GH + ((t + 2) % 3) * 1536;
      const float ghr = ld_af(&ghs[j]);
      const float ghz = ld_af(&ghs[j + 512]);
      const float ghn = ld_af(&ghs[j + 1024]);
      int bf;
      while (((bf = ld_lds_acq(&bf_lds)) >> 6) < t) __builtin_amdgcn_s_sleep(1);
      const float* gi = ws + WS_GI + (size_t)(bf & 63) * 1536;
      const float gir = gi[j], giz = gi[j + 512], gin = gi[j + 1024];
      const float r = 1.0f / (1.0f + expf(-(gir + ghr)));
      const float z = 1.0f / (1.0f + expf(-(giz + ghz)));
      const float n = tanhf(gin + r * ghn);
      h_lds[j] = (1.0f - z) * n + z * h_lds[j];
    }
    __syncthreads();  // barrier A: h_t, sc_lds ready

    // store previous step's normalized attention weights (p in regs)
    if (t > 0 && lane < 2)
      attn[(size_t)(t - 1) * TENC + r0 + 2 * wave + lane] =
          (lane ? p1 : p0) * (1.0f / sc_lds[0]);
    if (t == MAXLEN) break;

    // ---- dots + early push: all operands in registers / LDS ----
    {
      const float4 hh0 = ((const float4*)h_lds)[lane];
      const float4 hh1 = ((const float4*)h_lds)[lane + 64];
      const float d0 = wred(dot8(k0a, k0b, hh0, hh1));
      const float d1 = wred(dot8(k1a, k1b, hh0, hh1));
      p0 = expf(d0 * SCALE);
      p1 = expf(d1 * SCALE);
      const float fold = p0 * Mr0 + p1 * Mr1;
      if (wave == 0) {
        // wave0: wait for the 15 other partials (intra-CU LDS spin), reduce,
        // and issue the 41 RMW adds BEFORE barrier C -> acks drain inside
        // the barrier, overlapped with waves 1-6's aux dots.
        while (ld_lds_acq(&pwc) < 15 * (t + 1)) __builtin_amdgcn_s_sleep(1);
        float s = fold;
#pragma unroll
        for (int w2 = 1; w2 < NW; ++w2) s += pw_lds[w2 * 48 + lane];
        if (lane < 41)
          atomicAdd(&ws[WS_ACC + (t % 3) * SLOT + g * GSTRIDE + lane], s);
      } else {
        if (lane < 41) pw_lds[wave * 48 + lane] = fold;
        if (lane == 0) inc_lds_rel(&pwc);
        if (wave >= 1 && wave <= 6) {  // gh_t row for step t+1
          const float d = wred(dot8(xa0, xa1, hh0, hh1));
          if (lane == 0)
            st_af(&ws[WS_GH + (t % 3) * 1536 + b * 6 + (wave - 1)], d + xb);
        } else if (wave == 7 && b >= 1 && b <= NV) {  // hp row
          const float d = wred(dot8(xa0, xa1, hh0, hh1));
          if (lane == 0)
            st_af(&ws[WS_ACC + (t % 3) * SLOT + HPOFF + (b - 1)], d + xb);
        } else if (wave == 15 && b < NG) {  // zero slot (t+1)%3 group b
          float* nx = ws + WS_ACC + ((t + 1) % 3) * SLOT + b * GSTRIDE;
          if (lane < 41) st_af(&nx[lane], 0.0f);
          else if (lane >= 48 && lane < 56)
            st_ai((int*)&nx[CREP + 16 * (lane - 48)], 0);
        }
      }
    }
    __syncthreads();  // barrier C: adds/gh/hp/zero all performed at MALL

    // ---- release: 8 replica RMWs, relaxed, fire-and-forget ----
    if (tid == 0) {
      int* cbase = (int*)(ws + WS_ACC + (t % 3) * SLOT + g * GSTRIDE + CREP);
#pragma unroll
      for (int r = 0; r < 8; ++r) add_relaxed(cbase + 16 * r);
    }
  }
}

extern "C" void kernel_launch(void* const* d_in, const int* in_sizes, int n_in,
                              void* d_out, int out_size, void* d_ws,
                              size_t ws_size, hipStream_t stream) {
  const float* enc    = (const float*)d_in[0];
  const float* hidden = (const float*)d_in[1];
  const float* embed  = (const float*)d_in[2];
  const float* w_ih   = (const float*)d_in[3];
  const float* w_hh   = (const float*)d_in[4];
  const float* b_ih   = (const float*)d_in[5];
  const float* b_hh   = (const float*)d_in[6];
  const float* w_out  = (const float*)d_in[7];
  const float* b_out  = (const float*)d_in[8];
  float* out = (float*)d_out;
  float* ws  = (float*)d_ws;

  dec_init<<<dim3(1), dim3(NT), 0, stream>>>((int*)d_ws);
  dec_main<<<dim3(NB), dim3(NT), 0, stream>>>(enc, hidden, embed, w_ih, w_hh,
                                              b_ih, b_hh, w_out, b_out, out,
                                              ws);
}

// Round 11
// 3538.258 us; speedup vs baseline: 1.0107x; 1.0107x over previous
//
#include <hip/hip_runtime.h>
#include <math.h>

// ---------------------------------------------------------------------------
// TDS decoder R15: R13 (993us) + x4-replicated gather data + hp lines.
//  R13 proved MALL hot-line camping costs ~1 serialized serve per reader and
//  replication divides it (counter replicas: 256->32 readers/line, -34%).
//  R14 proved the opposite pole (serialize through one gatherer) is 3.6x bad.
//  This round applies R13's mechanism to the remaining camped structure on
//  the critical path: the one-shot gather of 64 group regions + hp.
//   - data replica r at float offset 48*r within the region (GSTRIDE 320);
//     counters (8 replicas) at 192+16*c. Producers: 4 pipelined atomicAdds
//     per lane (acks drain in barrier C; R11 proved >=1 RT slack there).
//     Readers: replica b&3 -> 64 readers/line (was 256).
//   - hp x4 (wave7 stores 4 copies; reader picks b&3).
//  Everything else byte-identical to R13 (replicated counter poll, early
//  push via pwc, 3-slot rotation, LDS go/bf flags, per-block full decide).
// ---------------------------------------------------------------------------

#define NV      40
#define TENC    8192
#define MAXLEN  200
#define EOS_IDX 38
#define NB      256
#define NT      1024
#define NW      16
#define ROWS    32
#define NG      64                    /* groups of NB/NG=4 blocks           */
#define GSTRIDE 320                   /* floats per group region            */
#define CREP    192                   /* first replica counter col          */
#define HPOFF   (NG * GSTRIDE)        /* 20480: hp replicas within slot     */
#define SLOT    (HPOFF + 256)         /* 20736 floats per rotation slot     */
#define SCALE   0.04419417382415922f  /* 1/sqrt(512) */

#define WS_ACC  128                   /* float[3][SLOT]                     */
#define WS_GH   (WS_ACC + 3 * SLOT)   /* 62336: float[3][1536]              */
#define WS_GI   (WS_GH + 3 * 1536)    /* 66944: float[40*1536]              */
/* total = 66944 + 61440 = 128384 floats (513 KB) */

__device__ __forceinline__ int ld_ai(int* p) {
  return __hip_atomic_load(p, __ATOMIC_RELAXED, __HIP_MEMORY_SCOPE_AGENT);
}
__device__ __forceinline__ float ld_af(float* p) {
  return __hip_atomic_load(p, __ATOMIC_RELAXED, __HIP_MEMORY_SCOPE_AGENT);
}
__device__ __forceinline__ void st_af(float* p, float v) {
  __hip_atomic_store(p, v, __ATOMIC_RELAXED, __HIP_MEMORY_SCOPE_AGENT);
}
__device__ __forceinline__ void st_ai(int* p, int v) {
  __hip_atomic_store(p, v, __ATOMIC_RELAXED, __HIP_MEMORY_SCOPE_AGENT);
}
__device__ __forceinline__ void add_relaxed(int* p) {
  __hip_atomic_fetch_add(p, 1, __ATOMIC_RELAXED, __HIP_MEMORY_SCOPE_AGENT);
}
__device__ __forceinline__ int ld_lds_acq(int* p) {
  return __hip_atomic_load(p, __ATOMIC_ACQUIRE, __HIP_MEMORY_SCOPE_WORKGROUP);
}
__device__ __forceinline__ void st_lds_rel(int* p, int v) {
  __hip_atomic_store(p, v, __ATOMIC_RELEASE, __HIP_MEMORY_SCOPE_WORKGROUP);
}
__device__ __forceinline__ void inc_lds_rel(int* p) {
  __hip_atomic_fetch_add(p, 1, __ATOMIC_RELEASE, __HIP_MEMORY_SCOPE_WORKGROUP);
}

__device__ __forceinline__ float wred(float s) {
#pragma unroll
  for (int o = 32; o > 0; o >>= 1) s += __shfl_xor(s, o, 64);
  return s;
}
__device__ __forceinline__ float dot8(float4 a0, float4 a1, float4 b0,
                                      float4 b1) {
  return a0.x * b0.x + a0.y * b0.y + a0.z * b0.z + a0.w * b0.w +
         a1.x * b1.x + a1.y * b1.y + a1.z * b1.z + a1.w * b1.w;
}
__device__ __forceinline__ float wdot512(const float* __restrict__ a,
                                         const float* __restrict__ b) {
  const int l = threadIdx.x & 63;
  const float4 a0 = ((const float4*)a)[l];
  const float4 a1 = ((const float4*)a)[l + 64];
  const float4 b0 = ((const float4*)b)[l];
  const float4 b1 = ((const float4*)b)[l + 64];
  return wred(dot8(a0, a1, b0, b1));
}

__global__ void dec_init(int* wsi) {
  for (int k = threadIdx.x; k < WS_GH; k += NT) wsi[k] = 0;
}

__global__ void __launch_bounds__(NT, 4) dec_main(
    const float* __restrict__ enc, const float* __restrict__ hidden,
    const float* __restrict__ embed, const float* __restrict__ w_ih,
    const float* __restrict__ w_hh, const float* __restrict__ b_ih,
    const float* __restrict__ b_hh, const float* __restrict__ w_out,
    const float* __restrict__ b_out, float* __restrict__ o,
    float* __restrict__ ws) {
  const int b = blockIdx.x, tid = threadIdx.x;
  const int wave = tid >> 6, lane = tid & 63;
  const int g = b & (NG - 1);
  const int rep = b & 7;
  const int dsel = (b & 3) * 48;   /* data replica offset   */
  const int hsel = (b & 3) * 64;   /* hp replica offset     */
  const int r0 = b * ROWS;

  __shared__ __align__(16) float h_lds[512];
  __shared__ float pw_lds[NW * 48];
  __shared__ float sc_lds[1];
  __shared__ int go_lds;  // t+1 when step-t inputs are at the MALL
  __shared__ int bf_lds;  // (t<<6)|best
  __shared__ int pwc;     // monotonic: waves 1-15 inc once per dots phase

  // ----------------- prologue -----------------
  if (tid < 512) h_lds[tid] = hidden[tid];
  if (tid == 0) { go_lds = 0; bf_lds = -1; pwc = 0; }

  // gi_all[v][j] = W_ih[j].embed[v] + b_ih[j]  (240 dots per block)
  for (int u = wave; u < 240; u += NW) {
    const int gl = b * 240 + u;
    const int v = gl / 1536, j = gl - v * 1536;
    const float d = wdot512(w_ih + (size_t)j * 512, embed + (size_t)v * 512);
    if (lane == 0) ws[WS_GI + (size_t)v * 1536 + j] = d + b_ih[j];
  }
  // gh(h0) -> slot 2  (waves 0-5, one row each)
  for (int jr = wave; jr < 6; jr += NW) {
    const int j = b * 6 + jr;
    const float d = wdot512(w_hh + (size_t)j * 512, hidden);
    if (lane == 0) st_af(&ws[WS_GH + 2 * 1536 + j], d + b_hh[j]);
  }
  __syncthreads();  // drain stores
  if (tid == 0) {
    int* cbase = (int*)(ws + WS_ACC + 2 * SLOT + g * GSTRIDE + CREP);
#pragma unroll
    for (int r = 0; r < 8; ++r) add_relaxed(cbase + 16 * r);
  }

  // --- register-resident operands ---
  const float* k0p = enc + (size_t)(r0 + 2 * wave) * 1024;
  const float4 k0a = ((const float4*)k0p)[lane];
  const float4 k0b = ((const float4*)k0p)[lane + 64];
  const float4 k1a = ((const float4*)(k0p + 1024))[lane];
  const float4 k1b = ((const float4*)(k0p + 1024))[lane + 64];

  // M columns: Mr0/Mr1 = W_out[lane,:512].V[row0/1]; lane40 = 1 (S column)
  float Mr0 = (lane == 40) ? 1.0f : 0.0f, Mr1 = Mr0;
  {
    const float* v0p = k0p + 512;
    const float4 va0 = ((const float4*)v0p)[lane];
    const float4 va1 = ((const float4*)v0p)[lane + 64];
    const float4 vb0 = ((const float4*)(v0p + 1024))[lane];
    const float4 vb1 = ((const float4*)(v0p + 1024))[lane + 64];
    for (int v = 0; v < NV; ++v) {
      const float* wp = w_out + (size_t)v * 1024;
      const float4 w0 = ((const float4*)wp)[lane];
      const float4 w1 = ((const float4*)wp)[lane + 64];
      const float sa = wred(dot8(va0, va1, w0, w1));
      const float sb = wred(dot8(vb0, vb1, w0, w1));
      if (lane == v) { Mr0 = sa; Mr1 = sb; }
    }
  }
  // aux row: waves 1-6 -> W_hh row b*6+wave-1; wave 7 (b in 1..40) -> W_out hp
  float4 xa0 = {0, 0, 0, 0}, xa1 = {0, 0, 0, 0};
  float xb = 0.0f;
  if (wave >= 1 && wave <= 6) {
    const int j = b * 6 + (wave - 1);
    const float* wp = w_hh + (size_t)j * 512;
    xa0 = ((const float4*)wp)[lane];
    xa1 = ((const float4*)wp)[lane + 64];
    xb = b_hh[j];
  } else if (wave == 7 && b >= 1 && b <= NV) {
    const float* wp = w_out + (size_t)(b - 1) * 1024 + 512;
    xa0 = ((const float4*)wp)[lane];
    xa1 = ((const float4*)wp)[lane + 64];
    xb = b_out[b - 1];
  }

  // ----------------- main loop -----------------
  int eos_reg = -1;              // block0/wave0/lane0 only
  float p0 = 0.0f, p1 = 0.0f;    // this wave's attention weights (unnorm.)
  float* attn = o + (size_t)MAXLEN * NV + 1;

  for (int t = 0; t <= MAXLEN; ++t) {
    if (wave == 0) {
      float* accs = ws + WS_ACC + ((t + 2) % 3) * SLOT;
      {  // poll all NG counters (sticky; replica b&7 -> 32 readers/line)
        int* cp = (int*)(accs + lane * GSTRIDE + CREP + 16 * rep);
        bool ok = false;
        for (;;) {
          if (!ok) ok = (ld_ai(cp) >= NB / NG);
          if (__ballot(!ok) == 0ull) break;
          __builtin_amdgcn_s_sleep(1);
        }
      }
      if (lane == 0) st_lds_rel(&go_lds, t + 1);  // GRU waves may start gh
      if (t > 0) {
        // hp first (replica b&3 -> 64 readers/line)
        const float hp = (lane < NV) ? ld_af(&accs[HPOFF + hsel + lane]) : 0.0f;
        // gather 64 group partials from replica b&3 (4 chains, pipelined)
        float c0 = 0, c1 = 0, c2 = 0, c3 = 0;
#pragma unroll
        for (int q = 0; q < NG / 4; ++q) {
          c0 += ld_af(&accs[(4 * q + 0) * GSTRIDE + dsel + lane]);
          c1 += ld_af(&accs[(4 * q + 1) * GSTRIDE + dsel + lane]);
          c2 += ld_af(&accs[(4 * q + 2) * GSTRIDE + dsel + lane]);
          c3 += ld_af(&accs[(4 * q + 3) * GSTRIDE + dsel + lane]);
        }
        const float cs = (c0 + c1) + (c2 + c3);
        const float S = __shfl(cs, NV, 64);
        const float ov = cs * (1.0f / S) + hp;
        unsigned long long key = 0ull;
        if (lane < NV) {
          unsigned u = __float_as_uint(ov);
          u = (u & 0x80000000u) ? ~u : (u | 0x80000000u);
          key = ((unsigned long long)u << 32) | (unsigned)(~lane);
        }
#pragma unroll
        for (int m = 32; m > 0; m >>= 1) {
          const unsigned long long k2 = __shfl_xor(key, m, 64);
          if (k2 > key) key = k2;
        }
        const int best = (int)(~(unsigned)key);
        if (b == 0 && lane < NV) o[(size_t)(t - 1) * NV + lane] = ov;
        if (lane == 0) {
          sc_lds[0] = S;
          if (b == 0) {
            if (best == EOS_IDX && eos_reg < 0) eos_reg = t - 1;
            if (t == MAXLEN)
              o[(size_t)MAXLEN * NV] =
                  (eos_reg < 0) ? (float)MAXLEN : (float)eos_reg;
          }
          st_lds_rel(&bf_lds, (t << 6) | best);
        }
      } else if (lane == 0) {
        st_lds_rel(&bf_lds, EOS_IDX);  // (0<<6)|EOS
      }
    } else if (wave >= 8 && t < MAXLEN) {
      // ---- GRU waves: gh loads overlap wave0's decide ----
      const int j = tid - 512;
      while (ld_lds_acq(&go_lds) < t + 1) __builtin_amdgcn_s_sleep(1);
      float* ghs = ws + WS_GH + ((t + 2) % 3) * 1536;
      const float ghr = ld_af(&ghs[j]);
      const float ghz = ld_af(&ghs[j + 512]);
      const float ghn = ld_af(&ghs[j + 1024]);
      int bf;
      while (((bf = ld_lds_acq(&bf_lds)) >> 6) < t) __builtin_amdgcn_s_sleep(1);
      const float* gi = ws + WS_GI + (size_t)(bf & 63) * 1536;
      const float gir = gi[j], giz = gi[j + 512], gin = gi[j + 1024];
      const float r = 1.0f / (1.0f + expf(-(gir + ghr)));
      const float z = 1.0f / (1.0f + expf(-(giz + ghz)));
      const float n = tanhf(gin + r * ghn);
      h_lds[j] = (1.0f - z) * n + z * h_lds[j];
    }
    __syncthreads();  // barrier A: h_t, sc_lds ready

    // store previous step's normalized attention weights (p in regs)
    if (t > 0 && lane < 2)
      attn[(size_t)(t - 1) * TENC + r0 + 2 * wave + lane] =
          (lane ? p1 : p0) * (1.0f / sc_lds[0]);
    if (t == MAXLEN) break;

    // ---- dots + early push: all operands in registers / LDS ----
    {
      const float4 hh0 = ((const float4*)h_lds)[lane];
      const float4 hh1 = ((const float4*)h_lds)[lane + 64];
      const float d0 = wred(dot8(k0a, k0b, hh0, hh1));
      const float d1 = wred(dot8(k1a, k1b, hh0, hh1));
      p0 = expf(d0 * SCALE);
      p1 = expf(d1 * SCALE);
      const float fold = p0 * Mr0 + p1 * Mr1;
      if (wave == 0) {
        // wave0: wait for the 15 other partials (intra-CU LDS spin), reduce,
        // and issue the 4x41 RMW adds BEFORE barrier C -> acks drain inside
        // the barrier, overlapped with waves 1-6's aux dots.
        while (ld_lds_acq(&pwc) < 15 * (t + 1)) __builtin_amdgcn_s_sleep(1);
        float s = fold;
#pragma unroll
        for (int w2 = 1; w2 < NW; ++w2) s += pw_lds[w2 * 48 + lane];
        if (lane < 41) {
          float* base = ws + WS_ACC + (t % 3) * SLOT + g * GSTRIDE + lane;
          atomicAdd(base, s);
          atomicAdd(base + 48, s);
          atomicAdd(base + 96, s);
          atomicAdd(base + 144, s);
        }
      } else {
        if (lane < 41) pw_lds[wave * 48 + lane] = fold;
        if (lane == 0) inc_lds_rel(&pwc);
        if (wave >= 1 && wave <= 6) {  // gh_t row for step t+1
          const float d = wred(dot8(xa0, xa1, hh0, hh1));
          if (lane == 0)
            st_af(&ws[WS_GH + (t % 3) * 1536 + b * 6 + (wave - 1)], d + xb);
        } else if (wave == 7 && b >= 1 && b <= NV) {  // hp row (x4 replicas)
          const float d = wred(dot8(xa0, xa1, hh0, hh1));
          if (lane == 0) {
            float* hb = ws + WS_ACC + (t % 3) * SLOT + HPOFF + (b - 1);
            st_af(hb, d + xb);
            st_af(hb + 64, d + xb);
            st_af(hb + 128, d + xb);
            st_af(hb + 192, d + xb);
          }
        } else if (wave == 15 && b < NG) {  // zero slot (t+1)%3 group b
          float* nx = ws + WS_ACC + ((t + 1) % 3) * SLOT + b * GSTRIDE;
          if (lane < 41) {
            st_af(&nx[lane], 0.0f);
            st_af(&nx[48 + lane], 0.0f);
            st_af(&nx[96 + lane], 0.0f);
            st_af(&nx[144 + lane], 0.0f);
          } else if (lane >= 48 && lane < 56) {
            st_ai((int*)&nx[CREP + 16 * (lane - 48)], 0);
          }
        }
      }
    }
    __syncthreads();  // barrier C: adds/gh/hp/zero all performed at MALL

    // ---- release: 8 replica RMWs, relaxed, fire-and-forget ----
    if (tid == 0) {
      int* cbase = (int*)(ws + WS_ACC + (t % 3) * SLOT + g * GSTRIDE + CREP);
#pragma unroll
      for (int r = 0; r < 8; ++r) add_relaxed(cbase + 16 * r);
    }
  }
}

extern "C" void kernel_launch(void* const* d_in, const int* in_sizes, int n_in,
                              void* d_out, int out_size, void* d_ws,
                              size_t ws_size, hipStream_t stream) {
  const float* enc    = (const float*)d_in[0];
  const float* hidden = (const float*)d_in[1];
  const float* embed  = (const float*)d_in[2];
  const float* w_ih   = (const float*)d_in[3];
  const float* w_hh   = (const float*)d_in[4];
  const float* b_ih   = (const float*)d_in[5];
  const float* b_hh   = (const float*)d_in[6];
  const float* w_out  = (const float*)d_in[7];
  const float* b_out  = (const float*)d_in[8];
  float* out = (float*)d_out;
  float* ws  = (float*)d_ws;

  dec_init<<<dim3(1), dim3(NT), 0, stream>>>((int*)d_ws);
  dec_main<<<dim3(NB), dim3(NT), 0, stream>>>(enc, hidden, embed, w_ih, w_hh,
                                              b_ih, b_hh, w_out, b_out, out,
                                              ws);
}

// Round 12
// 2247.842 us; speedup vs baseline: 1.5909x; 1.5741x over previous
//
#include <hip/hip_runtime.h>
#include <math.h>

// ---------------------------------------------------------------------------
// TDS decoder R16: R13 (993us) + three queue-tail cuts that respect the
// empirical laws from R13/R14/R15 (replicate read-camped lines; never add
// dependent hops; never multiply RMWs):
//  1) ROTATED gather: block b starts its 64-region chain at offset b
//     (region = (4q+c+b)&63). Spreads per-line arrival queue 256 -> ~4-8.
//     Zero cost (same loads, commutative sum).
//  2) gh x4 replicas: single-writer rows -> 3 extra plain stores/producer;
//     readers pick replica b&3 (64 readers/line, was 256).
//  3) hp x4 replicas: same, 3 extra stores from 40 blocks.
//  Everything else byte-identical to R13 (x8 replicated counters, early push
//  via pwc, 3-slot rotation, LDS go/bf flags, per-block full decide).
// ---------------------------------------------------------------------------

#define NV      40
#define TENC    8192
#define MAXLEN  200
#define EOS_IDX 38
#define NB      256
#define NT      1024
#define NW      16
#define ROWS    32
#define NG      64                    /* groups of NB/NG=4 blocks           */
#define GSTRIDE 192                   /* floats per group region            */
#define CREP    64                    /* first replica counter col          */
#define HPOFF   (NG * GSTRIDE)        /* 12288: hp replicas within slot     */
#define SLOT    (HPOFF + 256)         /* 12544 floats per rotation slot     */
#define GHSLOT  (4 * 1536)            /* gh slot stride (4 replicas)        */
#define SCALE   0.04419417382415922f  /* 1/sqrt(512) */

#define WS_ACC  128                   /* float[3][SLOT]                     */
#define WS_GH   (WS_ACC + 3 * SLOT)   /* 37760: float[3][4][1536]           */
#define WS_GI   (WS_GH + 3 * GHSLOT)  /* 56192: float[40*1536]              */
/* total = 56192 + 61440 = 117632 floats (470 KB) */

__device__ __forceinline__ int ld_ai(int* p) {
  return __hip_atomic_load(p, __ATOMIC_RELAXED, __HIP_MEMORY_SCOPE_AGENT);
}
__device__ __forceinline__ float ld_af(float* p) {
  return __hip_atomic_load(p, __ATOMIC_RELAXED, __HIP_MEMORY_SCOPE_AGENT);
}
__device__ __forceinline__ void st_af(float* p, float v) {
  __hip_atomic_store(p, v, __ATOMIC_RELAXED, __HIP_MEMORY_SCOPE_AGENT);
}
__device__ __forceinline__ void st_ai(int* p, int v) {
  __hip_atomic_store(p, v, __ATOMIC_RELAXED, __HIP_MEMORY_SCOPE_AGENT);
}
__device__ __forceinline__ void add_relaxed(int* p) {
  __hip_atomic_fetch_add(p, 1, __ATOMIC_RELAXED, __HIP_MEMORY_SCOPE_AGENT);
}
__device__ __forceinline__ int ld_lds_acq(int* p) {
  return __hip_atomic_load(p, __ATOMIC_ACQUIRE, __HIP_MEMORY_SCOPE_WORKGROUP);
}
__device__ __forceinline__ void st_lds_rel(int* p, int v) {
  __hip_atomic_store(p, v, __ATOMIC_RELEASE, __HIP_MEMORY_SCOPE_WORKGROUP);
}
__device__ __forceinline__ void inc_lds_rel(int* p) {
  __hip_atomic_fetch_add(p, 1, __ATOMIC_RELEASE, __HIP_MEMORY_SCOPE_WORKGROUP);
}

__device__ __forceinline__ float wred(float s) {
#pragma unroll
  for (int o = 32; o > 0; o >>= 1) s += __shfl_xor(s, o, 64);
  return s;
}
__device__ __forceinline__ float dot8(float4 a0, float4 a1, float4 b0,
                                      float4 b1) {
  return a0.x * b0.x + a0.y * b0.y + a0.z * b0.z + a0.w * b0.w +
         a1.x * b1.x + a1.y * b1.y + a1.z * b1.z + a1.w * b1.w;
}
__device__ __forceinline__ float wdot512(const float* __restrict__ a,
                                         const float* __restrict__ b) {
  const int l = threadIdx.x & 63;
  const float4 a0 = ((const float4*)a)[l];
  const float4 a1 = ((const float4*)a)[l + 64];
  const float4 b0 = ((const float4*)b)[l];
  const float4 b1 = ((const float4*)b)[l + 64];
  return wred(dot8(a0, a1, b0, b1));
}

__global__ void dec_init(int* wsi) {
  for (int k = threadIdx.x; k < WS_GH; k += NT) wsi[k] = 0;
}

__global__ void __launch_bounds__(NT, 4) dec_main(
    const float* __restrict__ enc, const float* __restrict__ hidden,
    const float* __restrict__ embed, const float* __restrict__ w_ih,
    const float* __restrict__ w_hh, const float* __restrict__ b_ih,
    const float* __restrict__ b_hh, const float* __restrict__ w_out,
    const float* __restrict__ b_out, float* __restrict__ o,
    float* __restrict__ ws) {
  const int b = blockIdx.x, tid = threadIdx.x;
  const int wave = tid >> 6, lane = tid & 63;
  const int g = b & (NG - 1);
  const int rep = b & 7;
  const int hsel = (b & 3) * 64;       /* hp replica offset   */
  const int gsel = (b & 3) * 1536;     /* gh replica offset   */
  const int r0 = b * ROWS;

  __shared__ __align__(16) float h_lds[512];
  __shared__ float pw_lds[NW * 48];
  __shared__ float sc_lds[1];
  __shared__ int go_lds;  // t+1 when step-t inputs are at the MALL
  __shared__ int bf_lds;  // (t<<6)|best
  __shared__ int pwc;     // monotonic: waves 1-15 inc once per dots phase

  // ----------------- prologue -----------------
  if (tid < 512) h_lds[tid] = hidden[tid];
  if (tid == 0) { go_lds = 0; bf_lds = -1; pwc = 0; }

  // gi_all[v][j] = W_ih[j].embed[v] + b_ih[j]  (240 dots per block)
  for (int u = wave; u < 240; u += NW) {
    const int gl = b * 240 + u;
    const int v = gl / 1536, j = gl - v * 1536;
    const float d = wdot512(w_ih + (size_t)j * 512, embed + (size_t)v * 512);
    if (lane == 0) ws[WS_GI + (size_t)v * 1536 + j] = d + b_ih[j];
  }
  // gh(h0) -> slot 2, all 4 replicas  (waves 0-5, one row each)
  for (int jr = wave; jr < 6; jr += NW) {
    const int j = b * 6 + jr;
    const float d = wdot512(w_hh + (size_t)j * 512, hidden);
    if (lane == 0) {
      float* gb = ws + WS_GH + 2 * GHSLOT + j;
      st_af(gb, d + b_hh[j]);
      st_af(gb + 1536, d + b_hh[j]);
      st_af(gb + 3072, d + b_hh[j]);
      st_af(gb + 4608, d + b_hh[j]);
    }
  }
  __syncthreads();  // drain stores
  if (tid == 0) {
    int* cbase = (int*)(ws + WS_ACC + 2 * SLOT + g * GSTRIDE + CREP);
#pragma unroll
    for (int r = 0; r < 8; ++r) add_relaxed(cbase + 16 * r);
  }

  // --- register-resident operands ---
  const float* k0p = enc + (size_t)(r0 + 2 * wave) * 1024;
  const float4 k0a = ((const float4*)k0p)[lane];
  const float4 k0b = ((const float4*)k0p)[lane + 64];
  const float4 k1a = ((const float4*)(k0p + 1024))[lane];
  const float4 k1b = ((const float4*)(k0p + 1024))[lane + 64];

  // M columns: Mr0/Mr1 = W_out[lane,:512].V[row0/1]; lane40 = 1 (S column)
  float Mr0 = (lane == 40) ? 1.0f : 0.0f, Mr1 = Mr0;
  {
    const float* v0p = k0p + 512;
    const float4 va0 = ((const float4*)v0p)[lane];
    const float4 va1 = ((const float4*)v0p)[lane + 64];
    const float4 vb0 = ((const float4*)(v0p + 1024))[lane];
    const float4 vb1 = ((const float4*)(v0p + 1024))[lane + 64];
    for (int v = 0; v < NV; ++v) {
      const float* wp = w_out + (size_t)v * 1024;
      const float4 w0 = ((const float4*)wp)[lane];
      const float4 w1 = ((const float4*)wp)[lane + 64];
      const float sa = wred(dot8(va0, va1, w0, w1));
      const float sb = wred(dot8(vb0, vb1, w0, w1));
      if (lane == v) { Mr0 = sa; Mr1 = sb; }
    }
  }
  // aux row: waves 1-6 -> W_hh row b*6+wave-1; wave 7 (b in 1..40) -> W_out hp
  float4 xa0 = {0, 0, 0, 0}, xa1 = {0, 0, 0, 0};
  float xb = 0.0f;
  if (wave >= 1 && wave <= 6) {
    const int j = b * 6 + (wave - 1);
    const float* wp = w_hh + (size_t)j * 512;
    xa0 = ((const float4*)wp)[lane];
    xa1 = ((const float4*)wp)[lane + 64];
    xb = b_hh[j];
  } else if (wave == 7 && b >= 1 && b <= NV) {
    const float* wp = w_out + (size_t)(b - 1) * 1024 + 512;
    xa0 = ((const float4*)wp)[lane];
    xa1 = ((const float4*)wp)[lane + 64];
    xb = b_out[b - 1];
  }

  // ----------------- main loop -----------------
  int eos_reg = -1;              // block0/wave0/lane0 only
  float p0 = 0.0f, p1 = 0.0f;    // this wave's attention weights (unnorm.)
  float* attn = o + (size_t)MAXLEN * NV + 1;

  for (int t = 0; t <= MAXLEN; ++t) {
    if (wave == 0) {
      float* accs = ws + WS_ACC + ((t + 2) % 3) * SLOT;
      {  // poll all NG counters (sticky; replica b&7 -> 32 readers/line)
        int* cp = (int*)(accs + lane * GSTRIDE + CREP + 16 * rep);
        bool ok = false;
        for (;;) {
          if (!ok) ok = (ld_ai(cp) >= NB / NG);
          if (__ballot(!ok) == 0ull) break;
          __builtin_amdgcn_s_sleep(1);
        }
      }
      if (lane == 0) st_lds_rel(&go_lds, t + 1);  // GRU waves may start gh
      if (t > 0) {
        // hp first (replica b&3 -> 64 readers/line)
        const float hp = (lane < NV) ? ld_af(&accs[HPOFF + hsel + lane]) : 0.0f;
        // gather 64 group partials, ROTATED start (spreads line queues)
        float c0 = 0, c1 = 0, c2 = 0, c3 = 0;
#pragma unroll
        for (int q = 0; q < NG / 4; ++q) {
          c0 += ld_af(&accs[((4 * q + 0 + b) & 63) * GSTRIDE + lane]);
          c1 += ld_af(&accs[((4 * q + 1 + b) & 63) * GSTRIDE + lane]);
          c2 += ld_af(&accs[((4 * q + 2 + b) & 63) * GSTRIDE + lane]);
          c3 += ld_af(&accs[((4 * q + 3 + b) & 63) * GSTRIDE + lane]);
        }
        const float cs = (c0 + c1) + (c2 + c3);
        const float S = __shfl(cs, NV, 64);
        const float ov = cs * (1.0f / S) + hp;
        unsigned long long key = 0ull;
        if (lane < NV) {
          unsigned u = __float_as_uint(ov);
          u = (u & 0x80000000u) ? ~u : (u | 0x80000000u);
          key = ((unsigned long long)u << 32) | (unsigned)(~lane);
        }
#pragma unroll
        for (int m = 32; m > 0; m >>= 1) {
          const unsigned long long k2 = __shfl_xor(key, m, 64);
          if (k2 > key) key = k2;
        }
        const int best = (int)(~(unsigned)key);
        if (b == 0 && lane < NV) o[(size_t)(t - 1) * NV + lane] = ov;
        if (lane == 0) {
          sc_lds[0] = S;
          if (b == 0) {
            if (best == EOS_IDX && eos_reg < 0) eos_reg = t - 1;
            if (t == MAXLEN)
              o[(size_t)MAXLEN * NV] =
                  (eos_reg < 0) ? (float)MAXLEN : (float)eos_reg;
          }
          st_lds_rel(&bf_lds, (t << 6) | best);
        }
      } else if (lane == 0) {
        st_lds_rel(&bf_lds, EOS_IDX);  // (0<<6)|EOS
      }
    } else if (wave >= 8 && t < MAXLEN) {
      // ---- GRU waves: gh loads (replica b&3) overlap wave0's decide ----
      const int j = tid - 512;
      while (ld_lds_acq(&go_lds) < t + 1) __builtin_amdgcn_s_sleep(1);
      float* ghs = ws + WS_GH + ((t + 2) % 3) * GHSLOT + gsel;
      const float ghr = ld_af(&ghs[j]);
      const float ghz = ld_af(&ghs[j + 512]);
      const float ghn = ld_af(&ghs[j + 1024]);
      int bf;
      while (((bf = ld_lds_acq(&bf_lds)) >> 6) < t) __builtin_amdgcn_s_sleep(1);
      const float* gi = ws + WS_GI + (size_t)(bf & 63) * 1536;
      const float gir = gi[j], giz = gi[j + 512], gin = gi[j + 1024];
      const float r = 1.0f / (1.0f + expf(-(gir + ghr)));
      const float z = 1.0f / (1.0f + expf(-(giz + ghz)));
      const float n = tanhf(gin + r * ghn);
      h_lds[j] = (1.0f - z) * n + z * h_lds[j];
    }
    __syncthreads();  // barrier A: h_t, sc_lds ready

    // store previous step's normalized attention weights (p in regs)
    if (t > 0 && lane < 2)
      attn[(size_t)(t - 1) * TENC + r0 + 2 * wave + lane] =
          (lane ? p1 : p0) * (1.0f / sc_lds[0]);
    if (t == MAXLEN) break;

    // ---- dots + early push: all operands in registers / LDS ----
    {
      const float4 hh0 = ((const float4*)h_lds)[lane];
      const float4 hh1 = ((const float4*)h_lds)[lane + 64];
      const float d0 = wred(dot8(k0a, k0b, hh0, hh1));
      const float d1 = wred(dot8(k1a, k1b, hh0, hh1));
      p0 = expf(d0 * SCALE);
      p1 = expf(d1 * SCALE);
      const float fold = p0 * Mr0 + p1 * Mr1;
      if (wave == 0) {
        // wave0: wait for the 15 other partials (intra-CU LDS spin), reduce,
        // and issue the 41 RMW adds BEFORE barrier C -> acks drain inside
        // the barrier, overlapped with waves 1-6's aux dots.
        while (ld_lds_acq(&pwc) < 15 * (t + 1)) __builtin_amdgcn_s_sleep(1);
        float s = fold;
#pragma unroll
        for (int w2 = 1; w2 < NW; ++w2) s += pw_lds[w2 * 48 + lane];
        if (lane < 41)
          atomicAdd(&ws[WS_ACC + (t % 3) * SLOT + g * GSTRIDE + lane], s);
      } else {
        if (lane < 41) pw_lds[wave * 48 + lane] = fold;
        if (lane == 0) inc_lds_rel(&pwc);
        if (wave >= 1 && wave <= 6) {  // gh_t row for step t+1 (x4 replicas)
          const float d = wred(dot8(xa0, xa1, hh0, hh1));
          if (lane == 0) {
            float* gb = ws + WS_GH + (t % 3) * GHSLOT + b * 6 + (wave - 1);
            st_af(gb, d + xb);
            st_af(gb + 1536, d + xb);
            st_af(gb + 3072, d + xb);
            st_af(gb + 4608, d + xb);
          }
        } else if (wave == 7 && b >= 1 && b <= NV) {  // hp row (x4 replicas)
          const float d = wred(dot8(xa0, xa1, hh0, hh1));
          if (lane == 0) {
            float* hb = ws + WS_ACC + (t % 3) * SLOT + HPOFF + (b - 1);
            st_af(hb, d + xb);
            st_af(hb + 64, d + xb);
            st_af(hb + 128, d + xb);
            st_af(hb + 192, d + xb);
          }
        } else if (wave == 15 && b < NG) {  // zero slot (t+1)%3 group b
          float* nx = ws + WS_ACC + ((t + 1) % 3) * SLOT + b * GSTRIDE;
          if (lane < 41) st_af(&nx[lane], 0.0f);
          else if (lane >= 48 && lane < 56)
            st_ai((int*)&nx[CREP + 16 * (lane - 48)], 0);
        }
      }
    }
    __syncthreads();  // barrier C: adds/gh/hp/zero all performed at MALL

    // ---- release: 8 replica RMWs, relaxed, fire-and-forget ----
    if (tid == 0) {
      int* cbase = (int*)(ws + WS_ACC + (t % 3) * SLOT + g * GSTRIDE + CREP);
#pragma unroll
      for (int r = 0; r < 8; ++r) add_relaxed(cbase + 16 * r);
    }
  }
}

extern "C" void kernel_launch(void* const* d_in, const int* in_sizes, int n_in,
                              void* d_out, int out_size, void* d_ws,
                              size_t ws_size, hipStream_t stream) {
  const float* enc    = (const float*)d_in[0];
  const float* hidden = (const float*)d_in[1];
  const float* embed  = (const float*)d_in[2];
  const float* w_ih   = (const float*)d_in[3];
  const float* w_hh   = (const float*)d_in[4];
  const float* b_ih   = (const float*)d_in[5];
  const float* b_hh   = (const float*)d_in[6];
  const float* w_out  = (const float*)d_in[7];
  const float* b_out  = (const float*)d_in[8];
  float* out = (float*)d_out;
  float* ws  = (float*)d_ws;

  dec_init<<<dim3(1), dim3(NT), 0, stream>>>((int*)d_ws);
  dec_main<<<dim3(NB), dim3(NT), 0, stream>>>(enc, hidden, embed, w_ih, w_hh,
                                              b_ih, b_hh, w_out, b_out, out,
                                              ws);
}

// Round 13
// 983.903 us; speedup vs baseline: 3.6346x; 2.2846x over previous
//
#include <hip/hip_runtime.h>
#include <math.h>

// ---------------------------------------------------------------------------
// TDS decoder R17 == R13 (verified 993us), the session's best kernel.
//  - x8 replicated release counters (poll: 32 desynchronized readers/line;
//    R13's -34% win). Producers: tid0 fires 8 relaxed fetch_adds post-barrier.
//  - Gather/gh/gi reads stay SYNCHRONIZED same-order broadcasts (MALL merges
//    them; R16 proved staggering defeats the merge, +126%).
//  - Early push (R11): waves 1-15 deposit fold partials + LDS counter inc,
//    wave0 reduces + issues 41 atomicAdds BEFORE barrier C (acks drain in
//    the barrier). Post-barrier publication = 8 replica RMWs only.
//  - 3-slot rotation, sticky counter poll, hp-first pipelined gather,
//    LDS go/bf flags, K/M/aux rows register-resident.
// ---------------------------------------------------------------------------

#define NV      40
#define TENC    8192
#define MAXLEN  200
#define EOS_IDX 38
#define NB      256
#define NT      1024
#define NW      16
#define ROWS    32
#define NG      64                    /* groups of NB/NG=4 blocks           */
#define GSTRIDE 192                   /* floats per group region            */
#define CREP    64                    /* first replica counter col          */
#define HPOFF   (NG * GSTRIDE)        /* 12288: hp line within slot         */
#define SLOT    (HPOFF + 64)          /* 12352 floats per rotation slot     */
#define SCALE   0.04419417382415922f  /* 1/sqrt(512) */

#define WS_ACC  128                   /* float[3][SLOT]                     */
#define WS_GH   (WS_ACC + 3 * SLOT)   /* 37184: float[3][1536]              */
#define WS_GI   (WS_GH + 3 * 1536)    /* 41792: float[40*1536]              */

__device__ __forceinline__ int ld_ai(int* p) {
  return __hip_atomic_load(p, __ATOMIC_RELAXED, __HIP_MEMORY_SCOPE_AGENT);
}
__device__ __forceinline__ float ld_af(float* p) {
  return __hip_atomic_load(p, __ATOMIC_RELAXED, __HIP_MEMORY_SCOPE_AGENT);
}
__device__ __forceinline__ void st_af(float* p, float v) {
  __hip_atomic_store(p, v, __ATOMIC_RELAXED, __HIP_MEMORY_SCOPE_AGENT);
}
__device__ __forceinline__ void st_ai(int* p, int v) {
  __hip_atomic_store(p, v, __ATOMIC_RELAXED, __HIP_MEMORY_SCOPE_AGENT);
}
__device__ __forceinline__ void add_relaxed(int* p) {
  __hip_atomic_fetch_add(p, 1, __ATOMIC_RELAXED, __HIP_MEMORY_SCOPE_AGENT);
}
__device__ __forceinline__ int ld_lds_acq(int* p) {
  return __hip_atomic_load(p, __ATOMIC_ACQUIRE, __HIP_MEMORY_SCOPE_WORKGROUP);
}
__device__ __forceinline__ void st_lds_rel(int* p, int v) {
  __hip_atomic_store(p, v, __ATOMIC_RELEASE, __HIP_MEMORY_SCOPE_WORKGROUP);
}
__device__ __forceinline__ void inc_lds_rel(int* p) {
  __hip_atomic_fetch_add(p, 1, __ATOMIC_RELEASE, __HIP_MEMORY_SCOPE_WORKGROUP);
}

__device__ __forceinline__ float wred(float s) {
#pragma unroll
  for (int o = 32; o > 0; o >>= 1) s += __shfl_xor(s, o, 64);
  return s;
}
__device__ __forceinline__ float dot8(float4 a0, float4 a1, float4 b0,
                                      float4 b1) {
  return a0.x * b0.x + a0.y * b0.y + a0.z * b0.z + a0.w * b0.w +
         a1.x * b1.x + a1.y * b1.y + a1.z * b1.z + a1.w * b1.w;
}
__device__ __forceinline__ float wdot512(const float* __restrict__ a,
                                         const float* __restrict__ b) {
  const int l = threadIdx.x & 63;
  const float4 a0 = ((const float4*)a)[l];
  const float4 a1 = ((const float4*)a)[l + 64];
  const float4 b0 = ((const float4*)b)[l];
  const float4 b1 = ((const float4*)b)[l + 64];
  return wred(dot8(a0, a1, b0, b1));
}

__global__ void dec_init(int* wsi) {
  for (int k = threadIdx.x; k < WS_GH; k += NT) wsi[k] = 0;
}

__global__ void __launch_bounds__(NT, 4) dec_main(
    const float* __restrict__ enc, const float* __restrict__ hidden,
    const float* __restrict__ embed, const float* __restrict__ w_ih,
    const float* __restrict__ w_hh, const float* __restrict__ b_ih,
    const float* __restrict__ b_hh, const float* __restrict__ w_out,
    const float* __restrict__ b_out, float* __restrict__ o,
    float* __restrict__ ws) {
  const int b = blockIdx.x, tid = threadIdx.x;
  const int wave = tid >> 6, lane = tid & 63;
  const int g = b & (NG - 1);
  const int rep = b & 7;
  const int r0 = b * ROWS;

  __shared__ __align__(16) float h_lds[512];
  __shared__ float pw_lds[NW * 48];
  __shared__ float sc_lds[1];
  __shared__ int go_lds;  // t+1 when step-t inputs are at the MALL
  __shared__ int bf_lds;  // (t<<6)|best
  __shared__ int pwc;     // monotonic: waves 1-15 inc once per dots phase

  // ----------------- prologue -----------------
  if (tid < 512) h_lds[tid] = hidden[tid];
  if (tid == 0) { go_lds = 0; bf_lds = -1; pwc = 0; }

  // gi_all[v][j] = W_ih[j].embed[v] + b_ih[j]  (240 dots per block)
  for (int u = wave; u < 240; u += NW) {
    const int gl = b * 240 + u;
    const int v = gl / 1536, j = gl - v * 1536;
    const float d = wdot512(w_ih + (size_t)j * 512, embed + (size_t)v * 512);
    if (lane == 0) ws[WS_GI + (size_t)v * 1536 + j] = d + b_ih[j];
  }
  // gh(h0) -> slot 2  (waves 0-5, one row each)
  for (int jr = wave; jr < 6; jr += NW) {
    const int j = b * 6 + jr;
    const float d = wdot512(w_hh + (size_t)j * 512, hidden);
    if (lane == 0) st_af(&ws[WS_GH + 2 * 1536 + j], d + b_hh[j]);
  }
  __syncthreads();  // drain stores
  if (tid == 0) {
    int* cbase = (int*)(ws + WS_ACC + 2 * SLOT + g * GSTRIDE + CREP);
#pragma unroll
    for (int r = 0; r < 8; ++r) add_relaxed(cbase + 16 * r);
  }

  // --- register-resident operands ---
  const float* k0p = enc + (size_t)(r0 + 2 * wave) * 1024;
  const float4 k0a = ((const float4*)k0p)[lane];
  const float4 k0b = ((const float4*)k0p)[lane + 64];
  const float4 k1a = ((const float4*)(k0p + 1024))[lane];
  const float4 k1b = ((const float4*)(k0p + 1024))[lane + 64];

  // M columns: Mr0/Mr1 = W_out[lane,:512].V[row0/1]; lane40 = 1 (S column)
  float Mr0 = (lane == 40) ? 1.0f : 0.0f, Mr1 = Mr0;
  {
    const float* v0p = k0p + 512;
    const float4 va0 = ((const float4*)v0p)[lane];
    const float4 va1 = ((const float4*)v0p)[lane + 64];
    const float4 vb0 = ((const float4*)(v0p + 1024))[lane];
    const float4 vb1 = ((const float4*)(v0p + 1024))[lane + 64];
    for (int v = 0; v < NV; ++v) {
      const float* wp = w_out + (size_t)v * 1024;
      const float4 w0 = ((const float4*)wp)[lane];
      const float4 w1 = ((const float4*)wp)[lane + 64];
      const float sa = wred(dot8(va0, va1, w0, w1));
      const float sb = wred(dot8(vb0, vb1, w0, w1));
      if (lane == v) { Mr0 = sa; Mr1 = sb; }
    }
  }
  // aux row: waves 1-6 -> W_hh row b*6+wave-1; wave 7 (b in 1..40) -> W_out hp
  float4 xa0 = {0, 0, 0, 0}, xa1 = {0, 0, 0, 0};
  float xb = 0.0f;
  if (wave >= 1 && wave <= 6) {
    const int j = b * 6 + (wave - 1);
    const float* wp = w_hh + (size_t)j * 512;
    xa0 = ((const float4*)wp)[lane];
    xa1 = ((const float4*)wp)[lane + 64];
    xb = b_hh[j];
  } else if (wave == 7 && b >= 1 && b <= NV) {
    const float* wp = w_out + (size_t)(b - 1) * 1024 + 512;
    xa0 = ((const float4*)wp)[lane];
    xa1 = ((const float4*)wp)[lane + 64];
    xb = b_out[b - 1];
  }

  // ----------------- main loop -----------------
  int eos_reg = -1;              // block0/wave0/lane0 only
  float p0 = 0.0f, p1 = 0.0f;    // this wave's attention weights (unnorm.)
  float* attn = o + (size_t)MAXLEN * NV + 1;

  for (int t = 0; t <= MAXLEN; ++t) {
    if (wave == 0) {
      float* accs = ws + WS_ACC + ((t + 2) % 3) * SLOT;
      {  // poll all NG counters (sticky; replica b&7 -> 32 readers/line)
        int* cp = (int*)(accs + lane * GSTRIDE + CREP + 16 * rep);
        bool ok = false;
        for (;;) {
          if (!ok) ok = (ld_ai(cp) >= NB / NG);
          if (__ballot(!ok) == 0ull) break;
          __builtin_amdgcn_s_sleep(1);
        }
      }
      if (lane == 0) st_lds_rel(&go_lds, t + 1);  // GRU waves may start gh
      if (t > 0) {
        // hp first (in-order vmcnt: result lands after one latency)
        const float hp = (lane < NV) ? ld_af(&accs[HPOFF + lane]) : 0.0f;
        // gather 64 group partials (4 chains, all loads pipelined,
        // SAME order across blocks -> MALL merges the broadcast)
        float c0 = 0, c1 = 0, c2 = 0, c3 = 0;
#pragma unroll
        for (int q = 0; q < NG / 4; ++q) {
          c0 += ld_af(&accs[(4 * q + 0) * GSTRIDE + lane]);
          c1 += ld_af(&accs[(4 * q + 1) * GSTRIDE + lane]);
          c2 += ld_af(&accs[(4 * q + 2) * GSTRIDE + lane]);
          c3 += ld_af(&accs[(4 * q + 3) * GSTRIDE + lane]);
        }
        const float cs = (c0 + c1) + (c2 + c3);
        const float S = __shfl(cs, NV, 64);
        const float ov = cs * (1.0f / S) + hp;
        unsigned long long key = 0ull;
        if (lane < NV) {
          unsigned u = __float_as_uint(ov);
          u = (u & 0x80000000u) ? ~u : (u | 0x80000000u);
          key = ((unsigned long long)u << 32) | (unsigned)(~lane);
        }
#pragma unroll
        for (int m = 32; m > 0; m >>= 1) {
          const unsigned long long k2 = __shfl_xor(key, m, 64);
          if (k2 > key) key = k2;
        }
        const int best = (int)(~(unsigned)key);
        if (b == 0 && lane < NV) o[(size_t)(t - 1) * NV + lane] = ov;
        if (lane == 0) {
          sc_lds[0] = S;
          if (b == 0) {
            if (best == EOS_IDX && eos_reg < 0) eos_reg = t - 1;
            if (t == MAXLEN)
              o[(size_t)MAXLEN * NV] =
                  (eos_reg < 0) ? (float)MAXLEN : (float)eos_reg;
          }
          st_lds_rel(&bf_lds, (t << 6) | best);
        }
      } else if (lane == 0) {
        st_lds_rel(&bf_lds, EOS_IDX);  // (0<<6)|EOS
      }
    } else if (wave >= 8 && t < MAXLEN) {
      // ---- GRU waves: gh loads overlap wave0's decide ----
      const int j = tid - 512;
      while (ld_lds_acq(&go_lds) < t + 1) __builtin_amdgcn_s_sleep(1);
      float* ghs = ws + WS_GH + ((t + 2) % 3) * 1536;
      const float ghr = ld_af(&ghs[j]);
      const float ghz = ld_af(&ghs[j + 512]);
      const float ghn = ld_af(&ghs[j + 1024]);
      int bf;
      while (((bf = ld_lds_acq(&bf_lds)) >> 6) < t) __builtin_amdgcn_s_sleep(1);
      const float* gi = ws + WS_GI + (size_t)(bf & 63) * 1536;
      const float gir = gi[j], giz = gi[j + 512], gin = gi[j + 1024];
      const float r = 1.0f / (1.0f + expf(-(gir + ghr)));
      const float z = 1.0f / (1.0f + expf(-(giz + ghz)));
      const float n = tanhf(gin + r * ghn);
      h_lds[j] = (1.0f - z) * n + z * h_lds[j];
    }
    __syncthreads();  // barrier A: h_t, sc_lds ready

    // store previous step's normalized attention weights (p in regs)
    if (t > 0 && lane < 2)
      attn[(size_t)(t - 1) * TENC + r0 + 2 * wave + lane] =
          (lane ? p1 : p0) * (1.0f / sc_lds[0]);
    if (t == MAXLEN) break;

    // ---- dots + early push: all operands in registers / LDS ----
    {
      const float4 hh0 = ((const float4*)h_lds)[lane];
      const float4 hh1 = ((const float4*)h_lds)[lane + 64];
      const float d0 = wred(dot8(k0a, k0b, hh0, hh1));
      const float d1 = wred(dot8(k1a, k1b, hh0, hh1));
      p0 = expf(d0 * SCALE);
      p1 = expf(d1 * SCALE);
      const float fold = p0 * Mr0 + p1 * Mr1;
      if (wave == 0) {
        // wave0: wait for the 15 other partials (intra-CU LDS spin), reduce,
        // and issue the 41 RMW adds BEFORE barrier C -> acks drain inside
        // the barrier, overlapped with waves 1-6's aux dots.
        while (ld_lds_acq(&pwc) < 15 * (t + 1)) __builtin_amdgcn_s_sleep(1);
        float s = fold;
#pragma unroll
        for (int w2 = 1; w2 < NW; ++w2) s += pw_lds[w2 * 48 + lane];
        if (lane < 41)
          atomicAdd(&ws[WS_ACC + (t % 3) * SLOT + g * GSTRIDE + lane], s);
      } else {
        if (lane < 41) pw_lds[wave * 48 + lane] = fold;
        if (lane == 0) inc_lds_rel(&pwc);
        if (wave >= 1 && wave <= 6) {  // gh_t row for step t+1
          const float d = wred(dot8(xa0, xa1, hh0, hh1));
          if (lane == 0)
            st_af(&ws[WS_GH + (t % 3) * 1536 + b * 6 + (wave - 1)], d + xb);
        } else if (wave == 7 && b >= 1 && b <= NV) {  // hp row
          const float d = wred(dot8(xa0, xa1, hh0, hh1));
          if (lane == 0)
            st_af(&ws[WS_ACC + (t % 3) * SLOT + HPOFF + (b - 1)], d + xb);
        } else if (wave == 15 && b < NG) {  // zero slot (t+1)%3 group b
          float* nx = ws + WS_ACC + ((t + 1) % 3) * SLOT + b * GSTRIDE;
          if (lane < 41) st_af(&nx[lane], 0.0f);
          else if (lane >= 48 && lane < 56)
            st_ai((int*)&nx[CREP + 16 * (lane - 48)], 0);
        }
      }
    }
    __syncthreads();  // barrier C: adds/gh/hp/zero all performed at MALL

    // ---- release: 8 replica RMWs, relaxed, fire-and-forget ----
    if (tid == 0) {
      int* cbase = (int*)(ws + WS_ACC + (t % 3) * SLOT + g * GSTRIDE + CREP);
#pragma unroll
      for (int r = 0; r < 8; ++r) add_relaxed(cbase + 16 * r);
    }
  }
}

extern "C" void kernel_launch(void* const* d_in, const int* in_sizes, int n_in,
                              void* d_out, int out_size, void* d_ws,
                              size_t ws_size, hipStream_t stream) {
  const float* enc    = (const float*)d_in[0];
  const float* hidden = (const float*)d_in[1];
  const float* embed  = (const float*)d_in[2];
  const float* w_ih   = (const float*)d_in[3];
  const float* w_hh   = (const float*)d_in[4];
  const float* b_ih   = (const float*)d_in[5];
  const float* b_hh   = (const float*)d_in[6];
  const float* w_out  = (const float*)d_in[7];
  const float* b_out  = (const float*)d_in[8];
  float* out = (float*)d_out;
  float* ws  = (float*)d_ws;

  dec_init<<<dim3(1), dim3(NT), 0, stream>>>((int*)d_ws);
  dec_main<<<dim3(NB), dim3(NT), 0, stream>>>(enc, hidden, embed, w_ih, w_hh,
                                              b_ih, b_hh, w_out, b_out, out,
                                              ws);
}